// Round 9
// baseline (34.531 us; speedup 1.0000x reference)
//
#include <hip/hip_runtime.h>
#include <hip/hip_bf16.h>

// LengthRegulator, single fused kernel, OUTPUT-partitioned, scatter-tok.
// out[b, j, :] = x[b, tok(j), :], tok(j) = searchsorted_right(csum, j) clipped.
//
// ROUND-7 STRUCTURE (best: 24.33 us) + nontemporal x loads.
// Grid: 16 batch rows x 64 windows = 1024 blocks (~4/CU, 24 waves/CU TLP —
// round 8 showed halving this regresses; TLP is the latency hider here).
// Per block:
//   1. scan: 256 threads load dur row (float4), wave shfl-scan + cross-wave
//      combine -> each scan thread holds its 4 tokens' csum in REGISTERS.
//   2. scatter: each scan thread writes tok[p-o0]=t for its intervals'
//      intersection with the window (no binary search, no cs[] array).
//   3. uniform store loop: 16 iterations/thread, compiler-scheduled (manual
//      8-deep batching regressed in round 8), nontemporal loads AND stores
//      (x is read exactly once; out is write-once streaming).
// B=16, T=1024, D=384, T_OUT=4096 (fixed by the reference).

#define LR_B     16
#define LR_T     1024
#define LR_D4    96      // 384 floats = 96 float4 per row
#define LR_TOUT  4096
#define LR_WIN   64      // output rows per block
#define LR_NWIN  (LR_TOUT / LR_WIN)   // 64 windows per batch row
#define LR_NTHR  384     // 6 waves: 96 float4-lanes x 4 row-slot groups

typedef float lr_f4 __attribute__((ext_vector_type(4)));

__device__ __forceinline__ int lr_count(float d) {
    return (int)floorf(fmaxf(d, 0.0f) + 0.5f);
}

__global__ __launch_bounds__(LR_NTHR) void lr_fused(
    const float* __restrict__ dur, const lr_f4* __restrict__ x,
    lr_f4* __restrict__ out) {
    const int blk  = blockIdx.x;         // b * 64 + w
    const int b    = blk >> 6;
    const int w    = blk & (LR_NWIN - 1);
    const int o0   = w * LR_WIN;
    const int tid  = threadIdx.x;
    const int lane = tid & 63;
    const int wid  = tid >> 6;

    __shared__ int tok[LR_WIN];          // token index per output row in window
    __shared__ int wbase[4];             // per-wave scan partials (waves 0..3)

    // ---- phase 1: csum of row b, kept in scan-thread registers ----
    const lr_f4* drow4 = (const lr_f4*)(dur + b * LR_T);
    int c0 = 0, c1 = 0, c2 = 0, c3 = 0, s = 0;
    if (tid < LR_T / 4) {                // threads 0..255, one float4 each
        lr_f4 dv = drow4[tid];
        c0 = lr_count(dv.x);
        c1 = c0 + lr_count(dv.y);
        c2 = c1 + lr_count(dv.z);
        c3 = c2 + lr_count(dv.w);
        s = c3;
    }
    int v = s;                           // inclusive wave scan of thread sums
    #pragma unroll
    for (int off = 1; off < 64; off <<= 1) {
        int u = __shfl_up(v, off, 64);
        if (lane >= off) v += u;
    }
    if (tid < LR_T / 4 && lane == 63) wbase[wid] = v;
    __syncthreads();

    // ---- phase 2: scatter token ids into the window's tok[] table ----
    if (tid < LR_T / 4) {
        int base = v - s;                // exclusive prefix within wave
        #pragma unroll
        for (int ww = 0; ww < 4; ++ww)
            if (ww < wid) base += wbase[ww];
        int pr = base;                   // running interval start
        const int ends[4] = {base + c0, base + c1, base + c2, base + c3};
        #pragma unroll
        for (int k = 0; k < 4; ++k) {
            const int t = tid * 4 + k;
            int st = pr, en = ends[k];
            pr = en;
            if (t == LR_T - 1) en = LR_TOUT;   // tail: searchsorted+clip
            int lo = max(st, o0), hi = min(en, o0 + LR_WIN);
            for (int p = lo; p < hi; ++p) tok[p - o0] = t;
        }
    }
    __syncthreads();

    // ---- phase 3: uniform copy loop (16 iterations, no divergence) ----
    const int g = tid / LR_D4;           // 0..3: row within 4-row slab
    const int d = tid - g * LR_D4;
    const lr_f4* xb = x + (size_t)b * LR_T * LR_D4 + d;
    lr_f4* ob = out + ((size_t)b * LR_TOUT + o0 + g) * LR_D4 + d;

    #pragma unroll
    for (int it = 0; it < LR_WIN / 4; ++it) {
        const int t = tok[it * 4 + g];   // LDS broadcast per 96-lane group
        lr_f4 val = __builtin_nontemporal_load(&xb[(size_t)t * LR_D4]);
        __builtin_nontemporal_store(val, &ob[(size_t)it * 4 * LR_D4]);
    }
}

extern "C" void kernel_launch(void* const* d_in, const int* in_sizes, int n_in,
                              void* d_out, int out_size, void* d_ws, size_t ws_size,
                              hipStream_t stream) {
    const float* x   = (const float*)d_in[0];   // [B, T, D] fp32
    const float* dur = (const float*)d_in[1];   // [B, T]    fp32
    // d_in[2] = out_len scalar (known: 4096)

    lr_fused<<<LR_B * LR_NWIN, LR_NTHR, 0, stream>>>(
        dur, (const lr_f4*)x, (lr_f4*)d_out);
}

// Round 10
// 24.002 us; speedup vs baseline: 1.4387x; 1.4387x over previous
//
#include <hip/hip_runtime.h>
#include <hip/hip_bf16.h>

// LengthRegulator, single fused kernel, OUTPUT-partitioned, scatter-tok.
// out[b, j, :] = x[b, tok(j), :], tok(j) = searchsorted_right(csum, j) clipped.
//
// ROUND-7 STRUCTURE (best: 24.33 us), WIN 64->32 for occupancy A/B.
// Grid: 16 batch rows x 128 windows = 2048 blocks -> 5 resident blocks/CU
// = 30 waves/CU (vs 24 at WIN=64); queued blocks' preambles overlap with
// resident blocks' store streams. Cost: 2x redundant dur scans (L2-hot).
// NOTE (round 9): x loads must stay CACHED — x rows are reused ~4x via L2;
// nontemporal loads forced HBM refetch (+42% time). nt-STORE only.
// NOTE (round 8): manual 8-deep load batching + 12 waves/CU regressed;
// TLP, not manual ILP, hides latency here.
// B=16, T=1024, D=384, T_OUT=4096 (fixed by the reference).

#define LR_B     16
#define LR_T     1024
#define LR_D4    96      // 384 floats = 96 float4 per row
#define LR_TOUT  4096
#define LR_WIN   32      // output rows per block
#define LR_NWIN  (LR_TOUT / LR_WIN)   // 128 windows per batch row
#define LR_NTHR  384     // 6 waves: 96 float4-lanes x 4 row-slot groups

typedef float lr_f4 __attribute__((ext_vector_type(4)));

__device__ __forceinline__ int lr_count(float d) {
    return (int)floorf(fmaxf(d, 0.0f) + 0.5f);
}

__global__ __launch_bounds__(LR_NTHR) void lr_fused(
    const float* __restrict__ dur, const lr_f4* __restrict__ x,
    lr_f4* __restrict__ out) {
    const int blk  = blockIdx.x;         // b * NWIN + w
    const int b    = blk >> 7;
    const int w    = blk & (LR_NWIN - 1);
    const int o0   = w * LR_WIN;
    const int tid  = threadIdx.x;
    const int lane = tid & 63;
    const int wid  = tid >> 6;

    __shared__ int tok[LR_WIN];          // token index per output row in window
    __shared__ int wbase[4];             // per-wave scan partials (waves 0..3)

    // ---- phase 1: csum of row b, kept in scan-thread registers ----
    const lr_f4* drow4 = (const lr_f4*)(dur + b * LR_T);
    int c0 = 0, c1 = 0, c2 = 0, c3 = 0, s = 0;
    if (tid < LR_T / 4) {                // threads 0..255, one float4 each
        lr_f4 dv = drow4[tid];
        c0 = lr_count(dv.x);
        c1 = c0 + lr_count(dv.y);
        c2 = c1 + lr_count(dv.z);
        c3 = c2 + lr_count(dv.w);
        s = c3;
    }
    int v = s;                           // inclusive wave scan of thread sums
    #pragma unroll
    for (int off = 1; off < 64; off <<= 1) {
        int u = __shfl_up(v, off, 64);
        if (lane >= off) v += u;
    }
    if (tid < LR_T / 4 && lane == 63) wbase[wid] = v;
    __syncthreads();

    // ---- phase 2: scatter token ids into the window's tok[] table ----
    if (tid < LR_T / 4) {
        int base = v - s;                // exclusive prefix within wave
        #pragma unroll
        for (int ww = 0; ww < 4; ++ww)
            if (ww < wid) base += wbase[ww];
        int pr = base;                   // running interval start
        const int ends[4] = {base + c0, base + c1, base + c2, base + c3};
        #pragma unroll
        for (int k = 0; k < 4; ++k) {
            const int t = tid * 4 + k;
            int st = pr, en = ends[k];
            pr = en;
            if (t == LR_T - 1) en = LR_TOUT;   // tail: searchsorted+clip
            int lo = max(st, o0), hi = min(en, o0 + LR_WIN);
            for (int p = lo; p < hi; ++p) tok[p - o0] = t;
        }
    }
    __syncthreads();

    // ---- phase 3: uniform copy loop (8 iterations, no divergence) ----
    const int g = tid / LR_D4;           // 0..3: row within 4-row slab
    const int d = tid - g * LR_D4;
    const lr_f4* xb = x + (size_t)b * LR_T * LR_D4 + d;
    lr_f4* ob = out + ((size_t)b * LR_TOUT + o0 + g) * LR_D4 + d;

    #pragma unroll
    for (int it = 0; it < LR_WIN / 4; ++it) {
        const int t = tok[it * 4 + g];   // LDS broadcast per 96-lane group
        lr_f4 val = xb[(size_t)t * LR_D4];              // CACHED load (L2 reuse)
        __builtin_nontemporal_store(val, &ob[(size_t)it * 4 * LR_D4]);
    }
}

extern "C" void kernel_launch(void* const* d_in, const int* in_sizes, int n_in,
                              void* d_out, int out_size, void* d_ws, size_t ws_size,
                              hipStream_t stream) {
    const float* x   = (const float*)d_in[0];   // [B, T, D] fp32
    const float* dur = (const float*)d_in[1];   // [B, T]    fp32
    // d_in[2] = out_len scalar (known: 4096)

    lr_fused<<<LR_B * LR_NWIN, LR_NTHR, 0, stream>>>(
        dur, (const lr_f4*)x, (lr_f4*)d_out);
}

// Round 11
// 23.982 us; speedup vs baseline: 1.4399x; 1.0008x over previous
//
#include <hip/hip_runtime.h>
#include <hip/hip_bf16.h>

// LengthRegulator, single fused kernel, OUTPUT-partitioned, scatter-tok.
// out[b, j, :] = x[b, tok(j), :], tok(j) = searchsorted_right(csum, j) clipped.
//
// FULL-RESIDENCY VARIANT: 256 threads (4 waves) x WIN=32 -> grid = 2048
// blocks = 8 blocks/CU x 256 CU: the ENTIRE grid is co-resident from t=0.
// Zero block turnover (no sequential cohorts, no per-cohort preamble stalls),
// 32 waves/CU (max). Scan maps perfectly: 256 threads x 1 float4 = 1024 durs.
// Phase 3 uses flat float4 indexing over the 32x96 window (row = f/96 via
// magic-mul), stores 4 KB contiguous per block-iteration, nontemporal.
// NOTE (round 9): x loads must stay CACHED (L1/L2 reuse ~4x); nt-load = +42%.
// NOTE (round 8): manual ILP batching regressed; TLP hides latency here.
// B=16, T=1024, D=384, T_OUT=4096 (fixed by the reference).

#define LR_B     16
#define LR_T     1024
#define LR_D4    96      // 384 floats = 96 float4 per row
#define LR_TOUT  4096
#define LR_WIN   32      // output rows per block
#define LR_NWIN  (LR_TOUT / LR_WIN)   // 128 windows per batch row
#define LR_NTHR  256     // 4 waves

typedef float lr_f4 __attribute__((ext_vector_type(4)));

__device__ __forceinline__ int lr_count(float d) {
    return (int)floorf(fmaxf(d, 0.0f) + 0.5f);
}

__global__ __launch_bounds__(LR_NTHR) void lr_fused(
    const float* __restrict__ dur, const lr_f4* __restrict__ x,
    lr_f4* __restrict__ out) {
    const int blk  = blockIdx.x;         // b * NWIN + w
    const int b    = blk >> 7;
    const int w    = blk & (LR_NWIN - 1);
    const int o0   = w * LR_WIN;
    const int tid  = threadIdx.x;
    const int lane = tid & 63;
    const int wid  = tid >> 6;

    __shared__ int tok[LR_WIN];          // token index per output row in window
    __shared__ int wbase[4];             // per-wave scan partials (waves 0..3)

    // ---- phase 1: csum of row b, kept in scan-thread registers ----
    const lr_f4* drow4 = (const lr_f4*)(dur + b * LR_T);
    lr_f4 dv = drow4[tid];               // 256 threads x 1 float4 = 1024 durs
    const int c0 = lr_count(dv.x);
    const int c1 = c0 + lr_count(dv.y);
    const int c2 = c1 + lr_count(dv.z);
    const int c3 = c2 + lr_count(dv.w);
    const int s  = c3;

    int v = s;                           // inclusive wave scan of thread sums
    #pragma unroll
    for (int off = 1; off < 64; off <<= 1) {
        int u = __shfl_up(v, off, 64);
        if (lane >= off) v += u;
    }
    if (lane == 63) wbase[wid] = v;
    __syncthreads();

    // ---- phase 2: scatter token ids into the window's tok[] table ----
    {
        int base = v - s;                // exclusive prefix within wave
        #pragma unroll
        for (int ww = 0; ww < 4; ++ww)
            if (ww < wid) base += wbase[ww];
        int pr = base;                   // running interval start
        const int ends[4] = {base + c0, base + c1, base + c2, base + c3};
        #pragma unroll
        for (int k = 0; k < 4; ++k) {
            const int t = tid * 4 + k;
            int st = pr, en = ends[k];
            pr = en;
            if (t == LR_T - 1) en = LR_TOUT;   // tail: searchsorted+clip
            int lo = max(st, o0), hi = min(en, o0 + LR_WIN);
            for (int p = lo; p < hi; ++p) tok[p - o0] = t;
        }
    }
    __syncthreads();

    // ---- phase 3: uniform flat copy loop (12 iterations, no divergence) ----
    // Window = 32 rows x 96 float4 = 3072 float4, flat-indexed by f.
    const lr_f4* xb = x + (size_t)b * LR_T * LR_D4;
    lr_f4* ob = out + ((size_t)b * LR_TOUT + o0) * LR_D4;

    #pragma unroll
    for (int it = 0; it < (LR_WIN * LR_D4) / LR_NTHR; ++it) {
        const int f   = it * LR_NTHR + tid;
        const int row = f / LR_D4;            // magic-mul div by 96
        const int d   = f - row * LR_D4;
        const int t   = tok[row];             // LDS read (near-broadcast per wave)
        lr_f4 val = xb[(size_t)t * LR_D4 + d];   // CACHED load (L1/L2 reuse)
        __builtin_nontemporal_store(val, &ob[f]);
    }
}

extern "C" void kernel_launch(void* const* d_in, const int* in_sizes, int n_in,
                              void* d_out, int out_size, void* d_ws, size_t ws_size,
                              hipStream_t stream) {
    const float* x   = (const float*)d_in[0];   // [B, T, D] fp32
    const float* dur = (const float*)d_in[1];   // [B, T]    fp32
    // d_in[2] = out_len scalar (known: 4096)

    lr_fused<<<LR_B * LR_NWIN, LR_NTHR, 0, stream>>>(
        dur, (const lr_f4*)x, (lr_f4*)d_out);
}